// Round 9
// baseline (283.071 us; speedup 1.0000x reference)
//
#include <hip/hip_runtime.h>
#include <hip/hip_bf16.h>
#include <math.h>

#define HIDDEN 2048
#define NHEADS 16
#define NKV 4
#define HD 128
#define SEQ 2048
#define BATCH 2
#define MTOT (BATCH*SEQ)     // 4096
#define NQ (NHEADS*HD)       // 2048
#define NKVD (NKV*HD)        // 512
#define NQKV (NQ + 2*NKVD)   // 3072

typedef __attribute__((ext_vector_type(8))) short short8;
typedef __attribute__((ext_vector_type(4))) float float4v;

#if __has_builtin(__builtin_amdgcn_exp2f)
#define EXP2F __builtin_amdgcn_exp2f
#else
#define EXP2F exp2f
#endif
#define C1 0.1275174f   // (1/sqrt(128)) * log2(e)

static __device__ __forceinline__ unsigned short f2bf(float f) {
  union { float f; unsigned int u; } v; v.f = f;
  unsigned int r = v.u + 0x7FFF + ((v.u >> 16) & 1);
  return (unsigned short)(r >> 16);
}
static __device__ __forceinline__ float bf2f(unsigned short h) {
  union { unsigned int u; float f; } v; v.u = ((unsigned int)h) << 16;
  return v.f;
}

// async global->LDS, 16B per lane; LDS dest = uniform base + lane*16
static __device__ __forceinline__ void async16(const unsigned short* g, unsigned short* l) {
  __builtin_amdgcn_global_load_lds(
      (const __attribute__((address_space(1))) unsigned int*)g,
      (__attribute__((address_space(3))) unsigned int*)l, 16, 0, 0);
}

// ------------- merged prep: cast x (fp32->bf16) + transpose 4 weights ----------
__global__ void prep(const float* __restrict__ x, unsigned short* __restrict__ xb,
                     const float* __restrict__ Wq, const float* __restrict__ Wk,
                     const float* __restrict__ Wv, const float* __restrict__ Wo,
                     unsigned short* __restrict__ Wqt, unsigned short* __restrict__ Wkt,
                     unsigned short* __restrict__ Wvt, unsigned short* __restrict__ Wot) {
  __shared__ float tile[32][33];
  int bx = blockIdx.x;
  if (bx < 8192) {
    int i = (bx * 256 + threadIdx.x) * 4;
    float4 v = *(const float4*)(x + i);
    ushort4 o;
    o.x = f2bf(v.x); o.y = f2bf(v.y); o.z = f2bf(v.z); o.w = f2bf(v.w);
    *(ushort4*)(xb + i) = o;
    return;
  }
  int bz = bx - 8192;            // 0..10239
  int tbx = bz % 160, tby = bz / 160;
  const int K = 2048;
  const float* W; unsigned short* Wt; int N; int tn;
  if (tbx < 64)      { W = Wq; Wt = Wqt; N = NQ;     tn = tbx * 32; }
  else if (tbx < 80) { W = Wk; Wt = Wkt; N = NKVD;   tn = (tbx - 64) * 32; }
  else if (tbx < 96) { W = Wv; Wt = Wvt; N = NKVD;   tn = (tbx - 80) * 32; }
  else               { W = Wo; Wt = Wot; N = HIDDEN; tn = (tbx - 96) * 32; }
  int tk = tby * 32;
  int tx = threadIdx.x & 31;
  int ty = threadIdx.x >> 5;  // 0..7
  #pragma unroll
  for (int i = 0; i < 4; i++) {
    int k = tk + ty + i * 8;
    tile[ty + i * 8][tx] = W[(size_t)k * N + tn + tx];
  }
  __syncthreads();
  #pragma unroll
  for (int i = 0; i < 4; i++) {
    int n = tn + ty + i * 8;
    Wt[(size_t)n * K + tk + tx] = f2bf(tile[tx][ty + i * 8]);
  }
}

// ======== fused QKV GEMM, 256^2 tile, 16 waves + fused K-RoPE (round-8) ========
// Q/V blocks: 4x4 wave grid (per-wave 64x64, acc[4][4]) as before.
// K blocks (bx 8,9): 8x2 wave grid (per-wave 32 rows x 128 cols = one full head)
// so the RoPE pair (d, d+64) = (acc[i][j], acc[i][j+4]) lives in the SAME lane ->
// rope applied to fp32 acc in registers at epilogue (single rounding; replaces
// the rope_k kernel entirely). 32 sincosf/lane only on 32 of 192 blocks' tails,
// hidden under other blocks' main loops.
__global__ __launch_bounds__(1024, 4) void gemm_qkv(
    const unsigned short* __restrict__ A,
    const unsigned short* __restrict__ Bt,
    unsigned short* __restrict__ Qb,
    unsigned short* __restrict__ Kb,
    unsigned short* __restrict__ Vt) {
  // ring slot: [A 256x32 | B 256x32] shorts = 32 KiB; x4 slots = 128 KiB
  __shared__ __align__(16) unsigned short L[4 * 16384];
  const int K = HIDDEN;          // 2048
  const int NT = K / 32;         // 64 K-tiles
  int bm = blockIdx.y * 256, bn = blockIdx.x * 256;
  int tid = threadIdx.x, w = tid >> 6, lane = tid & 63;
  int m16 = lane & 15, quad = lane >> 4;
  int r = tid >> 2, lch = tid & 3;           // staging row/chunk (256 rows x 4 chunks)
  int lchs = lch ^ ((r >> 1) & 3);           // swizzled staging piece
  int qx = quad ^ ((m16 >> 1) & 3);          // swizzled read piece
  const unsigned short* Agp = A + (size_t)(bm + r) * K + lchs * 8;
  const unsigned short* Bgp = Bt + (size_t)(bn + r) * K + lchs * 8;

  auto stage = [&](int t) {
    unsigned short* Lb = L + (t & 3) * 16384;
    int k0 = t * 32;
    async16(Agp + k0, Lb + tid * 8);
    async16(Bgp + k0, Lb + 8192 + tid * 8);
  };

  const bool isV = (blockIdx.x >= 10);
  const bool isK = (blockIdx.x >= 8 && blockIdx.x < 10);

  // prologue: tiles 0 and 1 in flight; wait tile 0 (leave tile 1's 2), barrier
  stage(0); stage(1);
  asm volatile("s_waitcnt vmcnt(2)" ::: "memory");
  __builtin_amdgcn_s_barrier();
  __builtin_amdgcn_sched_barrier(0);

  if (isK) {
    // 8x2 wave grid: rows wrow2*32, cols wcol2*128
    int wrow2 = w >> 1, wcol2 = w & 1;
    float4v acc[2][8];
    #pragma unroll
    for (int i = 0; i < 2; i++)
      #pragma unroll
      for (int j = 0; j < 8; j++) acc[i][j] = (float4v)0.0f;
    for (int t = 0; t < NT; ++t) {
      if (t + 2 < NT) stage(t + 2);
      const unsigned short* Ab_ = L + (t & 3) * 16384;
      const unsigned short* Bb_ = Ab_ + 8192;
      short8 af[2], bfr[8];
      #pragma unroll
      for (int i = 0; i < 2; i++)
        af[i] = *(const short8*)(&Ab_[(wrow2 * 32 + i * 16 + m16) * 32 + qx * 8]);
      #pragma unroll
      for (int j = 0; j < 8; j++)
        bfr[j] = *(const short8*)(&Bb_[(wcol2 * 128 + j * 16 + m16) * 32 + qx * 8]);
      __builtin_amdgcn_s_setprio(1);
      #pragma unroll
      for (int i = 0; i < 2; i++)
        #pragma unroll
        for (int j = 0; j < 8; j++)
          acc[i][j] = __builtin_amdgcn_mfma_f32_16x16x32_bf16(af[i], bfr[j], acc[i][j], 0, 0, 0);
      __builtin_amdgcn_s_setprio(0);
      if (t + 2 < NT) { asm volatile("s_waitcnt vmcnt(2)" ::: "memory"); }
      else            { asm volatile("s_waitcnt vmcnt(0)" ::: "memory"); }
      __builtin_amdgcn_s_barrier();
      __builtin_amdgcn_sched_barrier(0);
    }
    // epilogue: in-register RoPE on fp32 acc, then bf16 store.
    // col = (bn-2048) + wcol2*128 + j*16 + m16; d = j*16+m16 (<64 for j<4);
    // pair d+64 = acc[i][j+4]. angle = (row%SEQ) * 10000^(-d/64).
    #pragma unroll
    for (int i = 0; i < 2; i++)
      #pragma unroll
      for (int rr = 0; rr < 4; rr++) {
        int row = bm + wrow2 * 32 + i * 16 + quad * 4 + rr;
        float spos = (float)(row & (SEQ - 1));
        #pragma unroll
        for (int j = 0; j < 4; j++) {
          int d = j * 16 + m16;
          float inv = exp2f((float)d * -0.2076205059304601f);
          float sn, cs;
          sincosf(spos * inv, &sn, &cs);
          float f1 = acc[i][j][rr], f2 = acc[i][j + 4][rr];
          int col = (bn - 2048) + wcol2 * 128 + j * 16 + m16;
          Kb[(size_t)row * NKVD + col]      = f2bf(f1 * cs - f2 * sn);
          Kb[(size_t)row * NKVD + col + 64] = f2bf(f2 * cs + f1 * sn);
        }
      }
  } else if (!isV) {
    int wrow = w >> 2, wcol = w & 3;
    float4v acc[4][4];
    #pragma unroll
    for (int i = 0; i < 4; i++)
      #pragma unroll
      for (int j = 0; j < 4; j++) acc[i][j] = (float4v)0.0f;
    for (int t = 0; t < NT; ++t) {
      if (t + 2 < NT) stage(t + 2);
      const unsigned short* Ab_ = L + (t & 3) * 16384;
      const unsigned short* Bb_ = Ab_ + 8192;
      short8 af[4], bfr[4];
      #pragma unroll
      for (int i = 0; i < 4; i++)
        af[i] = *(const short8*)(&Ab_[(wrow * 64 + i * 16 + m16) * 32 + qx * 8]);
      #pragma unroll
      for (int j = 0; j < 4; j++)
        bfr[j] = *(const short8*)(&Bb_[(wcol * 64 + j * 16 + m16) * 32 + qx * 8]);
      __builtin_amdgcn_s_setprio(1);
      #pragma unroll
      for (int i = 0; i < 4; i++)
        #pragma unroll
        for (int j = 0; j < 4; j++)
          acc[i][j] = __builtin_amdgcn_mfma_f32_16x16x32_bf16(af[i], bfr[j], acc[i][j], 0, 0, 0);
      __builtin_amdgcn_s_setprio(0);
      if (t + 2 < NT) { asm volatile("s_waitcnt vmcnt(2)" ::: "memory"); }
      else            { asm volatile("s_waitcnt vmcnt(0)" ::: "memory"); }
      __builtin_amdgcn_s_barrier();
      __builtin_amdgcn_sched_barrier(0);
    }
    #pragma unroll
    for (int i = 0; i < 4; i++)
      #pragma unroll
      for (int j = 0; j < 4; j++)
        #pragma unroll
        for (int rr = 0; rr < 4; rr++) {
          int row = bm + wrow * 64 + i * 16 + quad * 4 + rr;
          int col = bn + wcol * 64 + j * 16 + m16;
          Qb[(size_t)row * NQ + col] = f2bf(acc[i][j][rr]);
        }
  } else {
    int wrow = w >> 2, wcol = w & 3;
    float4v acc[4][4];
    #pragma unroll
    for (int i = 0; i < 4; i++)
      #pragma unroll
      for (int j = 0; j < 4; j++) acc[i][j] = (float4v)0.0f;
    for (int t = 0; t < NT; ++t) {
      if (t + 2 < NT) stage(t + 2);
      const unsigned short* Ab_ = L + (t & 3) * 16384;
      const unsigned short* Bb_ = Ab_ + 8192;
      short8 af[4], bfr[4];
      #pragma unroll
      for (int i = 0; i < 4; i++)
        af[i] = *(const short8*)(&Ab_[(wrow * 64 + i * 16 + m16) * 32 + qx * 8]);
      #pragma unroll
      for (int j = 0; j < 4; j++)
        bfr[j] = *(const short8*)(&Bb_[(wcol * 64 + j * 16 + m16) * 32 + qx * 8]);
      __builtin_amdgcn_s_setprio(1);
      #pragma unroll
      for (int i = 0; i < 4; i++)
        #pragma unroll
        for (int j = 0; j < 4; j++)
          acc[i][j] = __builtin_amdgcn_mfma_f32_16x16x32_bf16(bfr[j], af[i], acc[i][j], 0, 0, 0);
      __builtin_amdgcn_s_setprio(0);
      if (t + 2 < NT) { asm volatile("s_waitcnt vmcnt(2)" ::: "memory"); }
      else            { asm volatile("s_waitcnt vmcnt(0)" ::: "memory"); }
      __builtin_amdgcn_s_barrier();
      __builtin_amdgcn_sched_barrier(0);
    }
    // swapped layout: row(quad*4+rr) = f-tile j, col(m16) = m-tile i
    #pragma unroll
    for (int i = 0; i < 4; i++)
      #pragma unroll
      for (int j = 0; j < 4; j++)
        #pragma unroll
        for (int rr = 0; rr < 4; rr++) {
          int f = bn - 2560 + wcol * 64 + j * 16 + quad * 4 + rr;
          int m = bm + wrow * 64 + i * 16 + m16;
          Vt[(size_t)f * MTOT + m] = f2bf(acc[i][j][rr]);
        }
  }
}

// ====== O-projection GEMM, 128^2 tile, 8 waves (round-5 TLP fix, kept) =========
__global__ __launch_bounds__(512, 4) void gemm_o(
    const unsigned short* __restrict__ A,
    const unsigned short* __restrict__ Bt,
    float* __restrict__ C, int M, int N, int K) {
  __shared__ __align__(16) unsigned short L[4 * 8192];  // 4 slots x 16 KiB
  const int NT = K / 32;         // 64
  int bm = blockIdx.y * 128, bn = blockIdx.x * 128;
  int tid = threadIdx.x, w = tid >> 6, lane = tid & 63;
  int wrow = w >> 2, wcol = w & 3;           // per-wave 64 rows x 32 cols
  int m16 = lane & 15, quad = lane >> 4;
  int r = tid >> 2, lch = tid & 3;           // staging: 128 rows x 4 chunks
  int lchs = lch ^ ((r >> 1) & 3);
  int qx = quad ^ ((m16 >> 1) & 3);
  const unsigned short* Agp = A + (size_t)(bm + r) * K + lchs * 8;
  const unsigned short* Bgp = Bt + (size_t)(bn + r) * K + lchs * 8;

  float4v acc[4][2];
  #pragma unroll
  for (int i = 0; i < 4; i++)
    #pragma unroll
    for (int j = 0; j < 2; j++) acc[i][j] = (float4v)0.0f;

  auto stage = [&](int t) {
    unsigned short* Lb = L + (t & 3) * 8192;
    int k0 = t * 32;
    async16(Agp + k0, Lb + tid * 8);
    async16(Bgp + k0, Lb + 4096 + tid * 8);
  };

  stage(0); stage(1);
  asm volatile("s_waitcnt vmcnt(2)" ::: "memory");
  __builtin_amdgcn_s_barrier();
  __builtin_amdgcn_sched_barrier(0);

  for (int t = 0; t < NT; ++t) {
    if (t + 2 < NT) stage(t + 2);
    const unsigned short* Ab_ = L + (t & 3) * 8192;
    const unsigned short* Bb_ = Ab_ + 4096;
    short8 af[4], bfr[2];
    #pragma unroll
    for (int i = 0; i < 4; i++)
      af[i] = *(const short8*)(&Ab_[(wrow * 64 + i * 16 + m16) * 32 + qx * 8]);
    #pragma unroll
    for (int j = 0; j < 2; j++)
      bfr[j] = *(const short8*)(&Bb_[(wcol * 32 + j * 16 + m16) * 32 + qx * 8]);
    __builtin_amdgcn_s_setprio(1);
    #pragma unroll
    for (int i = 0; i < 4; i++)
      #pragma unroll
      for (int j = 0; j < 2; j++)
        acc[i][j] = __builtin_amdgcn_mfma_f32_16x16x32_bf16(af[i], bfr[j], acc[i][j], 0, 0, 0);
    __builtin_amdgcn_s_setprio(0);
    if (t + 2 < NT) { asm volatile("s_waitcnt vmcnt(2)" ::: "memory"); }
    else            { asm volatile("s_waitcnt vmcnt(0)" ::: "memory"); }
    __builtin_amdgcn_s_barrier();
    __builtin_amdgcn_sched_barrier(0);
  }

  #pragma unroll
  for (int i = 0; i < 4; i++)
    #pragma unroll
    for (int j = 0; j < 2; j++)
      #pragma unroll
      for (int rr = 0; rr < 4; rr++) {
        int row = bm + wrow * 64 + i * 16 + quad * 4 + rr;
        int col = bn + wcol * 32 + j * 16 + m16;
        C[(size_t)row * N + col] = acc[i][j][rr];
      }
}

// ---- Flash attention: round-1 schedule + in-register sincosf Q-RoPE (r6 code) ---
// Q-RoPE in the prologue (32 one-time sincosf/lane; within-round A/B r6-vs-r7
// measured this at ~+1.5us — cheaper than rope_all's 32MB Qb pass).
#define FLASH_TILE(CUR, NXT)                                                  \
  {                                                                           \
    const int ktb = kt * 64;                                                  \
    __syncthreads(); /* TOP: all prior-iter LDS reads done, NXT dead */       \
    {                                                                         \
      const unsigned short* Vg = Vt + vgrow * (size_t)MTOT                    \
                                    + (size_t)b * SEQ + ktb + kcv * 32 + vlch * 8; \
      unsigned short* Vl = Vs + kcv * 4096 + ipv * 512;                       \
      _Pragma("unroll")                                                       \
      for (int i = 0; i < 4; i++) async16(Vg + (size_t)i * 16 * MTOT, Vl + i * 512); \
    }                                                                         \
    if (kt < H) {                                                             \
      const unsigned short* Kg = Kp + (((size_t)b * SEQ + (kt + 1) * 64 + lrow) * NKV + kvh) * HD + w * 32 + vlch * 8; \
      unsigned short* Kl = NXT + w * 2048;                                    \
      _Pragma("unroll")                                                       \
      for (int i = 0; i < 4; i++) async16(Kg + (size_t)i * 16 * NKV * HD, Kl + i * 512); \
    }                                                                         \
    const bool act1 = (ktb <= lmax_w);                                        \
    float4v sacc[2][4];                                                       \
    _Pragma("unroll") for (int s4 = 0; s4 < 4; s4++) {                        \
      sacc[0][s4] = (float4v)0.0f; sacc[1][s4] = (float4v)0.0f; }             \
    __builtin_amdgcn_s_setprio(1);                                            \
    if (act1) {                                                               \
      _Pragma("unroll")                                                       \
      for (int s4 = 0; s4 < 4; s4++)                                          \
        _Pragma("unroll")                                                     \
        for (int c = 0; c < 4; c++) {                                         \
          short8 kf = *(const short8*)(&CUR[c * 2048 + (s4 * 16 + m16) * 32 + qx * 8]); \
          sacc[0][s4] = __builtin_amdgcn_mfma_f32_16x16x32_bf16(kf, qf[0][c], sacc[0][s4], 0, 0, 0); \
          sacc[1][s4] = __builtin_amdgcn_mfma_f32_16x16x32_bf16(kf, qf[1][c], sacc[1][s4], 0, 0, 0); \
        }                                                                     \
    } else {                                                                  \
      _Pragma("unroll")                                                       \
      for (int s4 = 0; s4 < 4; s4++)                                          \
        _Pragma("unroll")                                                     \
        for (int c = 0; c < 4; c++) {                                         \
          short8 kf = *(const short8*)(&CUR[c * 2048 + (s4 * 16 + m16) * 32 + qx * 8]); \
          sacc[0][s4] = __builtin_amdgcn_mfma_f32_16x16x32_bf16(kf, qf[0][c], sacc[0][s4], 0, 0, 0); \
        }                                                                     \
    }                                                                         \
    __builtin_amdgcn_s_setprio(0);                                            \
    _Pragma("unroll")                                                         \
    for (int qs = 0; qs < 2; qs++) {                                          \
      if (qs == 0 || act1) {                                                  \
        const int tb = qs ? L : H;                                            \
        const int qabs = tb * 64 + w * 16 + m16;                              \
        const bool diag = (kt == tb);                                         \
        float sv[4][4]; float mloc = -1e30f;                                  \
        if (diag) {                                                           \
          _Pragma("unroll") for (int s4 = 0; s4 < 4; s4++)                    \
            _Pragma("unroll") for (int rr = 0; rr < 4; rr++) {                \
              int kabs = ktb + s4 * 16 + quad * 4 + rr;                       \
              float t = sacc[qs][s4][rr];                                     \
              sv[s4][rr] = (kabs > qabs) ? -1e30f : t;                        \
              mloc = fmaxf(mloc, sv[s4][rr]); }                               \
        } else {                                                              \
          _Pragma("unroll") for (int s4 = 0; s4 < 4; s4++)                    \
            _Pragma("unroll") for (int rr = 0; rr < 4; rr++) {                \
              sv[s4][rr] = sacc[qs][s4][rr]; mloc = fmaxf(mloc, sv[s4][rr]); } \
        }                                                                     \
        mloc *= C1;                                                           \
        mloc = fmaxf(mloc, __shfl_xor(mloc, 16, 64));                         \
        mloc = fmaxf(mloc, __shfl_xor(mloc, 32, 64));                         \
        float mnewS = fmaxf(miS[qs], mloc);                                   \
        const bool defer = (bool)__all(mloc <= miS[qs] + 8.0f);               \
        if (defer) mnewS = miS[qs]; /* T13: keep old max, P bounded by 2^8 */ \
        const int prow = qs * 64 + w * 16 + m16;                              \
        const int psw = prow * 32; const int rx = prow & 7;                   \
        float rs = 0.0f;                                                      \
        _Pragma("unroll") for (int s4 = 0; s4 < 4; s4++) {                    \
          float p0 = EXP2F(__builtin_fmaf(sv[s4][0], C1, -mnewS));            \
          float p1 = EXP2F(__builtin_fmaf(sv[s4][1], C1, -mnewS));            \
          float p2 = EXP2F(__builtin_fmaf(sv[s4][2], C1, -mnewS));            \
          float p3 = EXP2F(__builtin_fmaf(sv[s4][3], C1, -mnewS));            \
          rs += p0 + p1 + p2 + p3;                                            \
          uint2 u;                                                            \
          u.x = (__float_as_uint(p1) & 0xffff0000u) | (__float_as_uint(p0) >> 16); \
          u.y = (__float_as_uint(p3) & 0xffff0000u) | (__float_as_uint(p2) >> 16); \
          int chunkW = s4 * 2 + (quad >> 1);                                  \
          *(uint2*)(&Ps[psw + ((chunkW ^ rx) << 2) + (quad & 1) * 2]) = u;    \
        }                                                                     \
        rs += __shfl_xor(rs, 16, 64);                                         \
        rs += __shfl_xor(rs, 32, 64);                                         \
        if (!defer) {                                                         \
          const float alpha = EXP2F(miS[qs] - mnewS);                         \
          li[qs] *= alpha; miS[qs] = mnewS;                                   \
          _Pragma("unroll") for (int ds = 0; ds < 8; ds++) oacc[ds][qs] *= alpha; \
        }                                                                     \
        li[qs] += rs;                                                         \
      }                                                                       \
    }                                                                         \
    __syncthreads(); /* MID: drains V(kt)+K(kt+1), covered by S+softmax */    \
    {                                                                         \
      const int r0 = w * 16 + m16, r1 = 64 + w * 16 + m16;                    \
      __builtin_amdgcn_s_setprio(1);                                          \
      if (act1) {                                                             \
        _Pragma("unroll")                                                     \
        for (int kc = 0; kc < 2; kc++) {                                      \
          short8 pf0 = *(const short8*)(&Ps[r0 * 32 + (((kc * 4 + quad) ^ (r0 & 7)) << 2)]); \
          short8 pf1 = *(const short8*)(&Ps[r1 * 32 + (((kc * 4 + quad) ^ (r1 & 7)) << 2)]); \
          _Pragma("unroll")                                                   \
          for (int ds = 0; ds < 8; ds++) {                                    \
            short8 vf = *(const short8*)(&Vs[kc * 4096 + (ds * 16 + m16) * 32 + qx * 8]); \
            oacc[ds][0] = __builtin_amdgcn_mfma_f32_16x16x32_bf16(vf, pf0, oacc[ds][0], 0, 0, 0); \
            oacc[ds][1] = __builtin_amdgcn_mfma_f32_16x16x32_bf16(vf, pf1, oacc[ds][1], 0, 0, 0); \
          }                                                                   \
        }                                                                     \
      } else {                                                                \
        _Pragma("unroll")                                                     \
        for (int kc = 0; kc < 2; kc++) {                                      \
          short8 pf0 = *(const short8*)(&Ps[r0 * 32 + (((kc * 4 + quad) ^ (r0 & 7)) << 2)]); \
          _Pragma("unroll")                                                   \
          for (int ds = 0; ds < 8; ds++) {                                    \
            short8 vf = *(const short8*)(&Vs[kc * 4096 + (ds * 16 + m16) * 32 + qx * 8]); \
            oacc[ds][0] = __builtin_amdgcn_mfma_f32_16x16x32_bf16(vf, pf0, oacc[ds][0], 0, 0, 0); \
          }                                                                   \
        }                                                                     \
      }                                                                       \
      __builtin_amdgcn_s_setprio(0);                                          \
    }                                                                         \
  }

__global__ __launch_bounds__(256, 2) void flash_attn(
    const unsigned short* __restrict__ Q,
    const unsigned short* __restrict__ Kp,
    const unsigned short* __restrict__ Vt,
    unsigned short* __restrict__ O) {
  __shared__ unsigned short Ks0[4 * 64 * 32];  // 16 KB [dchunk][key][32d]
  __shared__ unsigned short Ks1[4 * 64 * 32];  // 16 KB
  __shared__ unsigned short Vs[2 * 128 * 32];  // 16 KB [kchunk][d][32seq]
  __shared__ unsigned int   Ps[128 * 32];      // 16 KB swizzled P[q][k/2]

  int bx = blockIdx.x;            // 0..15
  int h  = blockIdx.y;
  int b  = blockIdx.z;
  int kvh = h >> 2;
  int H = 31 - bx, L = bx;
  int tid = threadIdx.x;
  int w = tid >> 6, lane = tid & 63;
  int m16 = lane & 15, quad = lane >> 4;
  int lrow = lane >> 2, lch = lane & 3;
  const int vlch = lch ^ ((lrow >> 1) & 3);   // swizzled staging piece
  const int qx = quad ^ ((m16 >> 1) & 3);     // swizzled read piece
  const int lmax_w = L * 64 + w * 16 + 15;    // qs=1 active while ktb <= lmax_w

  const int kcv = w >> 1, ipv = (w & 1) * 4;
  const size_t vgrow = (size_t)kvh * HD + ipv * 16 + lrow;

  // qs=0 -> H-tile rows [H*64 + w*16, +16); qs=1 -> L-tile rows [L*64 + w*16, +16)
  short8 qf[2][4];
  #pragma unroll
  for (int qs = 0; qs < 2; qs++) {
    int tb = qs ? L : H;
    size_t qbase = (((size_t)b * SEQ + tb * 64 + w * 16 + m16) * NHEADS + h) * HD;
    #pragma unroll
    for (int c = 0; c < 4; c++)
      qf[qs][c] = *(const short8*)(Q + qbase + c * 32 + quad * 8);
  }
  // fused Q-RoPE (in-register): lane's dims c*32+quad*8+e; pairs (c,c+2) = (d,d+64)
  #pragma unroll
  for (int qs = 0; qs < 2; qs++) {
    int tb = qs ? L : H;
    float spos = (float)(tb * 64 + w * 16 + m16);
    #pragma unroll
    for (int c = 0; c < 2; c++) {
      #pragma unroll
      for (int e = 0; e < 8; e++) {
        int d = c * 32 + quad * 8 + e;
        float inv = exp2f((float)d * -0.2076205059304601f);
        float ang = spos * inv;
        float sn, cs;
        sincosf(ang, &sn, &cs);
        float f1 = bf2f((unsigned short)qf[qs][c][e]);
        float f2 = bf2f((unsigned short)qf[qs][c + 2][e]);
        qf[qs][c][e]     = (short)f2bf(f1 * cs - f2 * sn);
        qf[qs][c + 2][e] = (short)f2bf(f2 * cs + f1 * sn);
      }
    }
  }

  float4v oacc[8][2];
  #pragma unroll
  for (int ds = 0; ds < 8; ds++) { oacc[ds][0] = (float4v)0.0f; oacc[ds][1] = (float4v)0.0f; }
  float miS[2] = {-1e30f, -1e30f}, li[2] = {0.0f, 0.0f};

  // prologue: stage K(0) into Ks0 (drained at first TOP barrier)
  {
    const unsigned short* Kg = Kp + (((size_t)b * SEQ + lrow) * NKV + kvh) * HD + w * 32 + vlch * 8;
    unsigned short* Kl = Ks0 + w * 2048;
    #pragma unroll
    for (int i = 0; i < 4; i++) async16(Kg + (size_t)i * 16 * NKV * HD, Kl + i * 512);
  }

  int kt = 0;
  for (;;) {
    FLASH_TILE(Ks0, Ks1)
    if (++kt > H) break;
    FLASH_TILE(Ks1, Ks0)
    if (++kt > H) break;
  }

  #pragma unroll
  for (int qs = 0; qs < 2; qs++) {
    float inv = 1.0f / li[qs];
    int tb = qs ? L : H;
    int qabs = tb * 64 + w * 16 + m16;
    size_t obase = (((size_t)b * SEQ + qabs) * NHEADS + h) * HD + quad * 4;
    #pragma unroll
    for (int ds = 0; ds < 8; ds++) {
      float v0 = oacc[ds][qs][0] * inv;
      float v1 = oacc[ds][qs][1] * inv;
      float v2 = oacc[ds][qs][2] * inv;
      float v3 = oacc[ds][qs][3] * inv;
      uint2 u;
      u.x = ((unsigned)f2bf(v1) << 16) | f2bf(v0);
      u.y = ((unsigned)f2bf(v3) << 16) | f2bf(v2);
      *(uint2*)(O + obase + ds * 16) = u;
    }
  }
}

extern "C" void kernel_launch(void* const* d_in, const int* in_sizes, int n_in,
                              void* d_out, int out_size, void* d_ws, size_t ws_size,
                              hipStream_t stream) {
  const float* x  = (const float*)d_in[0];
  const float* Wq = (const float*)d_in[1];
  const float* Wk = (const float*)d_in[2];
  const float* Wv = (const float*)d_in[3];
  const float* Wo = (const float*)d_in[4];
  float* out = (float*)d_out;

  unsigned short* ws = (unsigned short*)d_ws;
  unsigned short* xb  = ws;                              // [4096][2048]
  unsigned short* Wqt = xb  + (size_t)MTOT * HIDDEN;     // [2048][2048] (Wqt/Wkt/Wvt contiguous = Wqkvt)
  unsigned short* Wkt = Wqt + (size_t)NQ * HIDDEN;       // [512][2048]
  unsigned short* Wvt = Wkt + (size_t)NKVD * HIDDEN;     // [512][2048]
  unsigned short* Wot = Wvt + (size_t)NKVD * HIDDEN;     // [2048][2048]
  unsigned short* Qb  = Wot + (size_t)NQ * HIDDEN;       // [4096][2048]
  unsigned short* Kb  = Qb  + (size_t)MTOT * NQ;         // [4096][512]
  unsigned short* Vtb = Kb  + (size_t)MTOT * NKVD;       // [512][4096]  (V^T)
  unsigned short* Ab  = Vtb + (size_t)MTOT * NKVD;       // [4096][2048]

  prep<<<8192 + 160 * 64, 256, 0, stream>>>(x, xb, Wq, Wk, Wv, Wo, Wqt, Wkt, Wvt, Wot);

  gemm_qkv<<<dim3(NQKV / 256, MTOT / 256), 1024, 0, stream>>>(xb, Wqt, Qb, Kb, Vtb);

  flash_attn<<<dim3(16, NHEADS, BATCH), 256, 0, stream>>>(Qb, Kb, Vtb, Ab);

  gemm_o<<<dim3(HIDDEN / 128, MTOT / 128), 512, 0, stream>>>(Ab, Wot, out, MTOT, HIDDEN, NQ);
}

// Round 10
// 277.345 us; speedup vs baseline: 1.0206x; 1.0206x over previous
//
#include <hip/hip_runtime.h>
#include <hip/hip_bf16.h>
#include <math.h>

#define HIDDEN 2048
#define NHEADS 16
#define NKV 4
#define HD 128
#define SEQ 2048
#define BATCH 2
#define MTOT (BATCH*SEQ)     // 4096
#define NQ (NHEADS*HD)       // 2048
#define NKVD (NKV*HD)        // 512
#define NQKV (NQ + 2*NKVD)   // 3072

typedef __attribute__((ext_vector_type(8))) short short8;
typedef __attribute__((ext_vector_type(4))) float float4v;

#if __has_builtin(__builtin_amdgcn_exp2f)
#define EXP2F __builtin_amdgcn_exp2f
#else
#define EXP2F exp2f
#endif
#define C1 0.1275174f   // (1/sqrt(128)) * log2(e)

static __device__ __forceinline__ unsigned short f2bf(float f) {
  union { float f; unsigned int u; } v; v.f = f;
  unsigned int r = v.u + 0x7FFF + ((v.u >> 16) & 1);
  return (unsigned short)(r >> 16);
}
static __device__ __forceinline__ float bf2f(unsigned short h) {
  union { unsigned int u; float f; } v; v.u = ((unsigned int)h) << 16;
  return v.f;
}

// async global->LDS, 16B per lane; LDS dest = uniform base + lane*16
static __device__ __forceinline__ void async16(const unsigned short* g, unsigned short* l) {
  __builtin_amdgcn_global_load_lds(
      (const __attribute__((address_space(1))) unsigned int*)g,
      (__attribute__((address_space(3))) unsigned int*)l, 16, 0, 0);
}

// ------------- merged prep: cast x (fp32->bf16) + transpose 4 weights ----------
__global__ void prep(const float* __restrict__ x, unsigned short* __restrict__ xb,
                     const float* __restrict__ Wq, const float* __restrict__ Wk,
                     const float* __restrict__ Wv, const float* __restrict__ Wo,
                     unsigned short* __restrict__ Wqt, unsigned short* __restrict__ Wkt,
                     unsigned short* __restrict__ Wvt, unsigned short* __restrict__ Wot) {
  __shared__ float tile[32][33];
  int bx = blockIdx.x;
  if (bx < 8192) {
    int i = (bx * 256 + threadIdx.x) * 4;
    float4 v = *(const float4*)(x + i);
    ushort4 o;
    o.x = f2bf(v.x); o.y = f2bf(v.y); o.z = f2bf(v.z); o.w = f2bf(v.w);
    *(ushort4*)(xb + i) = o;
    return;
  }
  int bz = bx - 8192;            // 0..10239
  int tbx = bz % 160, tby = bz / 160;
  const int K = 2048;
  const float* W; unsigned short* Wt; int N; int tn;
  if (tbx < 64)      { W = Wq; Wt = Wqt; N = NQ;     tn = tbx * 32; }
  else if (tbx < 80) { W = Wk; Wt = Wkt; N = NKVD;   tn = (tbx - 64) * 32; }
  else if (tbx < 96) { W = Wv; Wt = Wvt; N = NKVD;   tn = (tbx - 80) * 32; }
  else               { W = Wo; Wt = Wot; N = HIDDEN; tn = (tbx - 96) * 32; }
  int tk = tby * 32;
  int tx = threadIdx.x & 31;
  int ty = threadIdx.x >> 5;  // 0..7
  #pragma unroll
  for (int i = 0; i < 4; i++) {
    int k = tk + ty + i * 8;
    tile[ty + i * 8][tx] = W[(size_t)k * N + tn + tx];
  }
  __syncthreads();
  #pragma unroll
  for (int i = 0; i < 4; i++) {
    int n = tn + ty + i * 8;
    Wt[(size_t)n * K + tk + tx] = f2bf(tile[tx][ty + i * 8]);
  }
}

// ==== fused QKV GEMM, 256^2 tile, 16 waves + FULL RoPE fusion (round-9) ========
// Q and K blocks (bx<10) share one path: 8x2 wave grid (per-wave 32 rows x 128
// cols = one full head) -> the RoPE pair (d, d+64) = (acc[i][j], acc[i][j+4])
// lives in the SAME lane -> rope applied to fp32 acc at epilogue (single
// rounding; replaces rope_k AND flash's Q-RoPE prologue/table entirely).
// V blocks: swapped-operand 4x4 grid as before (V^T stores coalesced).
__global__ __launch_bounds__(1024, 4) void gemm_qkv(
    const unsigned short* __restrict__ A,
    const unsigned short* __restrict__ Bt,
    unsigned short* __restrict__ Qb,
    unsigned short* __restrict__ Kb,
    unsigned short* __restrict__ Vt) {
  // ring slot: [A 256x32 | B 256x32] shorts = 32 KiB; x4 slots = 128 KiB
  __shared__ __align__(16) unsigned short L[4 * 16384];
  const int K = HIDDEN;          // 2048
  const int NT = K / 32;         // 64 K-tiles
  int bm = blockIdx.y * 256, bn = blockIdx.x * 256;
  int tid = threadIdx.x, w = tid >> 6, lane = tid & 63;
  int m16 = lane & 15, quad = lane >> 4;
  int r = tid >> 2, lch = tid & 3;           // staging row/chunk (256 rows x 4 chunks)
  int lchs = lch ^ ((r >> 1) & 3);           // swizzled staging piece
  int qx = quad ^ ((m16 >> 1) & 3);          // swizzled read piece
  const unsigned short* Agp = A + (size_t)(bm + r) * K + lchs * 8;
  const unsigned short* Bgp = Bt + (size_t)(bn + r) * K + lchs * 8;

  auto stage = [&](int t) {
    unsigned short* Lb = L + (t & 3) * 16384;
    int k0 = t * 32;
    async16(Agp + k0, Lb + tid * 8);
    async16(Bgp + k0, Lb + 8192 + tid * 8);
  };

  const bool isV = (blockIdx.x >= 10);
  const bool isK = (blockIdx.x >= 8 && blockIdx.x < 10);

  // prologue: tiles 0 and 1 in flight; wait tile 0 (leave tile 1's 2), barrier
  stage(0); stage(1);
  asm volatile("s_waitcnt vmcnt(2)" ::: "memory");
  __builtin_amdgcn_s_barrier();
  __builtin_amdgcn_sched_barrier(0);

  if (!isV) {
    // Q and K: 8x2 wave grid (rows wrow2*32, cols wcol2*128 = one head)
    int wrow2 = w >> 1, wcol2 = w & 1;
    float4v acc[2][8];
    #pragma unroll
    for (int i = 0; i < 2; i++)
      #pragma unroll
      for (int j = 0; j < 8; j++) acc[i][j] = (float4v)0.0f;
    for (int t = 0; t < NT; ++t) {
      if (t + 2 < NT) stage(t + 2);
      const unsigned short* Ab_ = L + (t & 3) * 16384;
      const unsigned short* Bb_ = Ab_ + 8192;
      short8 af[2], bfr[8];
      #pragma unroll
      for (int i = 0; i < 2; i++)
        af[i] = *(const short8*)(&Ab_[(wrow2 * 32 + i * 16 + m16) * 32 + qx * 8]);
      #pragma unroll
      for (int j = 0; j < 8; j++)
        bfr[j] = *(const short8*)(&Bb_[(wcol2 * 128 + j * 16 + m16) * 32 + qx * 8]);
      __builtin_amdgcn_s_setprio(1);
      #pragma unroll
      for (int i = 0; i < 2; i++)
        #pragma unroll
        for (int j = 0; j < 8; j++)
          acc[i][j] = __builtin_amdgcn_mfma_f32_16x16x32_bf16(af[i], bfr[j], acc[i][j], 0, 0, 0);
      __builtin_amdgcn_s_setprio(0);
      if (t + 2 < NT) { asm volatile("s_waitcnt vmcnt(2)" ::: "memory"); }
      else            { asm volatile("s_waitcnt vmcnt(0)" ::: "memory"); }
      __builtin_amdgcn_s_barrier();
      __builtin_amdgcn_sched_barrier(0);
    }
    // epilogue: in-register RoPE on fp32 acc, then bf16 store.
    // head-local d = j*16+m16 (<64 for j<4); pair d+64 = acc[i][j+4].
    unsigned short* Out = isK ? Kb : Qb;
    const int ncols = isK ? NKVD : NQ;
    const int cb = isK ? bn - 2048 : bn;
    #pragma unroll
    for (int i = 0; i < 2; i++)
      #pragma unroll
      for (int rr = 0; rr < 4; rr++) {
        int row = bm + wrow2 * 32 + i * 16 + quad * 4 + rr;
        float spos = (float)(row & (SEQ - 1));
        #pragma unroll
        for (int j = 0; j < 4; j++) {
          int d = j * 16 + m16;
          float inv = exp2f((float)d * -0.2076205059304601f);
          float sn, cs;
          sincosf(spos * inv, &sn, &cs);
          float f1 = acc[i][j][rr], f2 = acc[i][j + 4][rr];
          int col = cb + wcol2 * 128 + j * 16 + m16;
          Out[(size_t)row * ncols + col]      = f2bf(f1 * cs - f2 * sn);
          Out[(size_t)row * ncols + col + 64] = f2bf(f2 * cs + f1 * sn);
        }
      }
  } else {
    int wrow = w >> 2, wcol = w & 3;
    float4v acc[4][4];
    #pragma unroll
    for (int i = 0; i < 4; i++)
      #pragma unroll
      for (int j = 0; j < 4; j++) acc[i][j] = (float4v)0.0f;
    for (int t = 0; t < NT; ++t) {
      if (t + 2 < NT) stage(t + 2);
      const unsigned short* Ab_ = L + (t & 3) * 16384;
      const unsigned short* Bb_ = Ab_ + 8192;
      short8 af[4], bfr[4];
      #pragma unroll
      for (int i = 0; i < 4; i++)
        af[i] = *(const short8*)(&Ab_[(wrow * 64 + i * 16 + m16) * 32 + qx * 8]);
      #pragma unroll
      for (int j = 0; j < 4; j++)
        bfr[j] = *(const short8*)(&Bb_[(wcol * 64 + j * 16 + m16) * 32 + qx * 8]);
      __builtin_amdgcn_s_setprio(1);
      #pragma unroll
      for (int i = 0; i < 4; i++)
        #pragma unroll
        for (int j = 0; j < 4; j++)
          acc[i][j] = __builtin_amdgcn_mfma_f32_16x16x32_bf16(bfr[j], af[i], acc[i][j], 0, 0, 0);
      __builtin_amdgcn_s_setprio(0);
      if (t + 2 < NT) { asm volatile("s_waitcnt vmcnt(2)" ::: "memory"); }
      else            { asm volatile("s_waitcnt vmcnt(0)" ::: "memory"); }
      __builtin_amdgcn_s_barrier();
      __builtin_amdgcn_sched_barrier(0);
    }
    // swapped layout: row(quad*4+rr) = f-tile j, col(m16) = m-tile i
    #pragma unroll
    for (int i = 0; i < 4; i++)
      #pragma unroll
      for (int j = 0; j < 4; j++)
        #pragma unroll
        for (int rr = 0; rr < 4; rr++) {
          int f = bn - 2560 + wcol * 64 + j * 16 + quad * 4 + rr;
          int m = bm + wrow * 64 + i * 16 + m16;
          Vt[(size_t)f * MTOT + m] = f2bf(acc[i][j][rr]);
        }
  }
}

// ====== O-projection GEMM, 128^2 tile, 8 waves (round-5 TLP fix, kept) =========
__global__ __launch_bounds__(512, 4) void gemm_o(
    const unsigned short* __restrict__ A,
    const unsigned short* __restrict__ Bt,
    float* __restrict__ C, int M, int N, int K) {
  __shared__ __align__(16) unsigned short L[4 * 8192];  // 4 slots x 16 KiB
  const int NT = K / 32;         // 64
  int bm = blockIdx.y * 128, bn = blockIdx.x * 128;
  int tid = threadIdx.x, w = tid >> 6, lane = tid & 63;
  int wrow = w >> 2, wcol = w & 3;           // per-wave 64 rows x 32 cols
  int m16 = lane & 15, quad = lane >> 4;
  int r = tid >> 2, lch = tid & 3;           // staging: 128 rows x 4 chunks
  int lchs = lch ^ ((r >> 1) & 3);
  int qx = quad ^ ((m16 >> 1) & 3);
  const unsigned short* Agp = A + (size_t)(bm + r) * K + lchs * 8;
  const unsigned short* Bgp = Bt + (size_t)(bn + r) * K + lchs * 8;

  float4v acc[4][2];
  #pragma unroll
  for (int i = 0; i < 4; i++)
    #pragma unroll
    for (int j = 0; j < 2; j++) acc[i][j] = (float4v)0.0f;

  auto stage = [&](int t) {
    unsigned short* Lb = L + (t & 3) * 8192;
    int k0 = t * 32;
    async16(Agp + k0, Lb + tid * 8);
    async16(Bgp + k0, Lb + 4096 + tid * 8);
  };

  stage(0); stage(1);
  asm volatile("s_waitcnt vmcnt(2)" ::: "memory");
  __builtin_amdgcn_s_barrier();
  __builtin_amdgcn_sched_barrier(0);

  for (int t = 0; t < NT; ++t) {
    if (t + 2 < NT) stage(t + 2);
    const unsigned short* Ab_ = L + (t & 3) * 8192;
    const unsigned short* Bb_ = Ab_ + 4096;
    short8 af[4], bfr[2];
    #pragma unroll
    for (int i = 0; i < 4; i++)
      af[i] = *(const short8*)(&Ab_[(wrow * 64 + i * 16 + m16) * 32 + qx * 8]);
    #pragma unroll
    for (int j = 0; j < 2; j++)
      bfr[j] = *(const short8*)(&Bb_[(wcol * 32 + j * 16 + m16) * 32 + qx * 8]);
    __builtin_amdgcn_s_setprio(1);
    #pragma unroll
    for (int i = 0; i < 4; i++)
      #pragma unroll
      for (int j = 0; j < 2; j++)
        acc[i][j] = __builtin_amdgcn_mfma_f32_16x16x32_bf16(af[i], bfr[j], acc[i][j], 0, 0, 0);
    __builtin_amdgcn_s_setprio(0);
    if (t + 2 < NT) { asm volatile("s_waitcnt vmcnt(2)" ::: "memory"); }
    else            { asm volatile("s_waitcnt vmcnt(0)" ::: "memory"); }
    __builtin_amdgcn_s_barrier();
    __builtin_amdgcn_sched_barrier(0);
  }

  #pragma unroll
  for (int i = 0; i < 4; i++)
    #pragma unroll
    for (int j = 0; j < 2; j++)
      #pragma unroll
      for (int rr = 0; rr < 4; rr++) {
        int row = bm + wrow * 64 + i * 16 + quad * 4 + rr;
        int col = bn + wcol * 32 + j * 16 + m16;
        C[(size_t)row * N + col] = acc[i][j][rr];
      }
}

// -------- Flash attention: round-1/5/7 measured-best schedule, no prologue ------
// (Q and K arrive already roped from gemm_qkv's fp32 epilogue; this is the
// byte-identical no-prologue flash that measured 66.0-66.8 (r1/r5) / 75.5 (r7).)
#define FLASH_TILE(CUR, NXT)                                                  \
  {                                                                           \
    const int ktb = kt * 64;                                                  \
    __syncthreads(); /* TOP: all prior-iter LDS reads done, NXT dead */       \
    {                                                                         \
      const unsigned short* Vg = Vt + vgrow * (size_t)MTOT                    \
                                    + (size_t)b * SEQ + ktb + kcv * 32 + vlch * 8; \
      unsigned short* Vl = Vs + kcv * 4096 + ipv * 512;                       \
      _Pragma("unroll")                                                       \
      for (int i = 0; i < 4; i++) async16(Vg + (size_t)i * 16 * MTOT, Vl + i * 512); \
    }                                                                         \
    if (kt < H) {                                                             \
      const unsigned short* Kg = Kp + (((size_t)b * SEQ + (kt + 1) * 64 + lrow) * NKV + kvh) * HD + w * 32 + vlch * 8; \
      unsigned short* Kl = NXT + w * 2048;                                    \
      _Pragma("unroll")                                                       \
      for (int i = 0; i < 4; i++) async16(Kg + (size_t)i * 16 * NKV * HD, Kl + i * 512); \
    }                                                                         \
    const bool act1 = (ktb <= lmax_w);                                        \
    float4v sacc[2][4];                                                       \
    _Pragma("unroll") for (int s4 = 0; s4 < 4; s4++) {                        \
      sacc[0][s4] = (float4v)0.0f; sacc[1][s4] = (float4v)0.0f; }             \
    __builtin_amdgcn_s_setprio(1);                                            \
    if (act1) {                                                               \
      _Pragma("unroll")                                                       \
      for (int s4 = 0; s4 < 4; s4++)                                          \
        _Pragma("unroll")                                                     \
        for (int c = 0; c < 4; c++) {                                         \
          short8 kf = *(const short8*)(&CUR[c * 2048 + (s4 * 16 + m16) * 32 + qx * 8]); \
          sacc[0][s4] = __builtin_amdgcn_mfma_f32_16x16x32_bf16(kf, qf[0][c], sacc[0][s4], 0, 0, 0); \
          sacc[1][s4] = __builtin_amdgcn_mfma_f32_16x16x32_bf16(kf, qf[1][c], sacc[1][s4], 0, 0, 0); \
        }                                                                     \
    } else {                                                                  \
      _Pragma("unroll")                                                       \
      for (int s4 = 0; s4 < 4; s4++)                                          \
        _Pragma("unroll")                                                     \
        for (int c = 0; c < 4; c++) {                                         \
          short8 kf = *(const short8*)(&CUR[c * 2048 + (s4 * 16 + m16) * 32 + qx * 8]); \
          sacc[0][s4] = __builtin_amdgcn_mfma_f32_16x16x32_bf16(kf, qf[0][c], sacc[0][s4], 0, 0, 0); \
        }                                                                     \
    }                                                                         \
    __builtin_amdgcn_s_setprio(0);                                            \
    _Pragma("unroll")                                                         \
    for (int qs = 0; qs < 2; qs++) {                                          \
      if (qs == 0 || act1) {                                                  \
        const int tb = qs ? L : H;                                            \
        const int qabs = tb * 64 + w * 16 + m16;                              \
        const bool diag = (kt == tb);                                         \
        float sv[4][4]; float mloc = -1e30f;                                  \
        if (diag) {                                                           \
          _Pragma("unroll") for (int s4 = 0; s4 < 4; s4++)                    \
            _Pragma("unroll") for (int rr = 0; rr < 4; rr++) {                \
              int kabs = ktb + s4 * 16 + quad * 4 + rr;                       \
              float t = sacc[qs][s4][rr];                                     \
              sv[s4][rr] = (kabs > qabs) ? -1e30f : t;                        \
              mloc = fmaxf(mloc, sv[s4][rr]); }                               \
        } else {                                                              \
          _Pragma("unroll") for (int s4 = 0; s4 < 4; s4++)                    \
            _Pragma("unroll") for (int rr = 0; rr < 4; rr++) {                \
              sv[s4][rr] = sacc[qs][s4][rr]; mloc = fmaxf(mloc, sv[s4][rr]); } \
        }                                                                     \
        mloc *= C1;                                                           \
        mloc = fmaxf(mloc, __shfl_xor(mloc, 16, 64));                         \
        mloc = fmaxf(mloc, __shfl_xor(mloc, 32, 64));                         \
        float mnewS = fmaxf(miS[qs], mloc);                                   \
        const bool defer = (bool)__all(mloc <= miS[qs] + 8.0f);               \
        if (defer) mnewS = miS[qs]; /* T13: keep old max, P bounded by 2^8 */ \
        const int prow = qs * 64 + w * 16 + m16;                              \
        const int psw = prow * 32; const int rx = prow & 7;                   \
        float rs = 0.0f;                                                      \
        _Pragma("unroll") for (int s4 = 0; s4 < 4; s4++) {                    \
          float p0 = EXP2F(__builtin_fmaf(sv[s4][0], C1, -mnewS));            \
          float p1 = EXP2F(__builtin_fmaf(sv[s4][1], C1, -mnewS));            \
          float p2 = EXP2F(__builtin_fmaf(sv[s4][2], C1, -mnewS));            \
          float p3 = EXP2F(__builtin_fmaf(sv[s4][3], C1, -mnewS));            \
          rs += p0 + p1 + p2 + p3;                                            \
          uint2 u;                                                            \
          u.x = (__float_as_uint(p1) & 0xffff0000u) | (__float_as_uint(p0) >> 16); \
          u.y = (__float_as_uint(p3) & 0xffff0000u) | (__float_as_uint(p2) >> 16); \
          int chunkW = s4 * 2 + (quad >> 1);                                  \
          *(uint2*)(&Ps[psw + ((chunkW ^ rx) << 2) + (quad & 1) * 2]) = u;    \
        }                                                                     \
        rs += __shfl_xor(rs, 16, 64);                                         \
        rs += __shfl_xor(rs, 32, 64);                                         \
        if (!defer) {                                                         \
          const float alpha = EXP2F(miS[qs] - mnewS);                         \
          li[qs] *= alpha; miS[qs] = mnewS;                                   \
          _Pragma("unroll") for (int ds = 0; ds < 8; ds++) oacc[ds][qs] *= alpha; \
        }                                                                     \
        li[qs] += rs;                                                         \
      }                                                                       \
    }                                                                         \
    __syncthreads(); /* MID: drains V(kt)+K(kt+1), covered by S+softmax */    \
    {                                                                         \
      const int r0 = w * 16 + m16, r1 = 64 + w * 16 + m16;                    \
      __builtin_amdgcn_s_setprio(1);                                          \
      if (act1) {                                                             \
        _Pragma("unroll")                                                     \
        for (int kc = 0; kc < 2; kc++) {                                      \
          short8 pf0 = *(const short8*)(&Ps[r0 * 32 + (((kc * 4 + quad) ^ (r0 & 7)) << 2)]); \
          short8 pf1 = *(const short8*)(&Ps[r1 * 32 + (((kc * 4 + quad) ^ (r1 & 7)) << 2)]); \
          _Pragma("unroll")                                                   \
          for (int ds = 0; ds < 8; ds++) {                                    \
            short8 vf = *(const short8*)(&Vs[kc * 4096 + (ds * 16 + m16) * 32 + qx * 8]); \
            oacc[ds][0] = __builtin_amdgcn_mfma_f32_16x16x32_bf16(vf, pf0, oacc[ds][0], 0, 0, 0); \
            oacc[ds][1] = __builtin_amdgcn_mfma_f32_16x16x32_bf16(vf, pf1, oacc[ds][1], 0, 0, 0); \
          }                                                                   \
        }                                                                     \
      } else {                                                                \
        _Pragma("unroll")                                                     \
        for (int kc = 0; kc < 2; kc++) {                                      \
          short8 pf0 = *(const short8*)(&Ps[r0 * 32 + (((kc * 4 + quad) ^ (r0 & 7)) << 2)]); \
          _Pragma("unroll")                                                   \
          for (int ds = 0; ds < 8; ds++) {                                    \
            short8 vf = *(const short8*)(&Vs[kc * 4096 + (ds * 16 + m16) * 32 + qx * 8]); \
            oacc[ds][0] = __builtin_amdgcn_mfma_f32_16x16x32_bf16(vf, pf0, oacc[ds][0], 0, 0, 0); \
          }                                                                   \
        }                                                                     \
      }                                                                       \
      __builtin_amdgcn_s_setprio(0);                                          \
    }                                                                         \
  }

__global__ __launch_bounds__(256, 2) void flash_attn(
    const unsigned short* __restrict__ Q,
    const unsigned short* __restrict__ Kp,
    const unsigned short* __restrict__ Vt,
    unsigned short* __restrict__ O) {
  __shared__ unsigned short Ks0[4 * 64 * 32];  // 16 KB [dchunk][key][32d]
  __shared__ unsigned short Ks1[4 * 64 * 32];  // 16 KB
  __shared__ unsigned short Vs[2 * 128 * 32];  // 16 KB [kchunk][d][32seq]
  __shared__ unsigned int   Ps[128 * 32];      // 16 KB swizzled P[q][k/2]

  int bx = blockIdx.x;            // 0..15
  int h  = blockIdx.y;
  int b  = blockIdx.z;
  int kvh = h >> 2;
  int H = 31 - bx, L = bx;
  int tid = threadIdx.x;
  int w = tid >> 6, lane = tid & 63;
  int m16 = lane & 15, quad = lane >> 4;
  int lrow = lane >> 2, lch = lane & 3;
  const int vlch = lch ^ ((lrow >> 1) & 3);   // swizzled staging piece
  const int qx = quad ^ ((m16 >> 1) & 3);     // swizzled read piece
  const int lmax_w = L * 64 + w * 16 + 15;    // qs=1 active while ktb <= lmax_w

  const int kcv = w >> 1, ipv = (w & 1) * 4;
  const size_t vgrow = (size_t)kvh * HD + ipv * 16 + lrow;

  // qs=0 -> H-tile rows [H*64 + w*16, +16); qs=1 -> L-tile rows [L*64 + w*16, +16)
  short8 qf[2][4];
  #pragma unroll
  for (int qs = 0; qs < 2; qs++) {
    int tb = qs ? L : H;
    size_t qbase = (((size_t)b * SEQ + tb * 64 + w * 16 + m16) * NHEADS + h) * HD;
    #pragma unroll
    for (int c = 0; c < 4; c++)
      qf[qs][c] = *(const short8*)(Q + qbase + c * 32 + quad * 8);
  }

  float4v oacc[8][2];
  #pragma unroll
  for (int ds = 0; ds < 8; ds++) { oacc[ds][0] = (float4v)0.0f; oacc[ds][1] = (float4v)0.0f; }
  float miS[2] = {-1e30f, -1e30f}, li[2] = {0.0f, 0.0f};

  // prologue: stage K(0) into Ks0 (drained at first TOP barrier)
  {
    const unsigned short* Kg = Kp + (((size_t)b * SEQ + lrow) * NKV + kvh) * HD + w * 32 + vlch * 8;
    unsigned short* Kl = Ks0 + w * 2048;
    #pragma unroll
    for (int i = 0; i < 4; i++) async16(Kg + (size_t)i * 16 * NKV * HD, Kl + i * 512);
  }

  int kt = 0;
  for (;;) {
    FLASH_TILE(Ks0, Ks1)
    if (++kt > H) break;
    FLASH_TILE(Ks1, Ks0)
    if (++kt > H) break;
  }

  #pragma unroll
  for (int qs = 0; qs < 2; qs++) {
    float inv = 1.0f / li[qs];
    int tb = qs ? L : H;
    int qabs = tb * 64 + w * 16 + m16;
    size_t obase = (((size_t)b * SEQ + qabs) * NHEADS + h) * HD + quad * 4;
    #pragma unroll
    for (int ds = 0; ds < 8; ds++) {
      float v0 = oacc[ds][qs][0] * inv;
      float v1 = oacc[ds][qs][1] * inv;
      float v2 = oacc[ds][qs][2] * inv;
      float v3 = oacc[ds][qs][3] * inv;
      uint2 u;
      u.x = ((unsigned)f2bf(v1) << 16) | f2bf(v0);
      u.y = ((unsigned)f2bf(v3) << 16) | f2bf(v2);
      *(uint2*)(O + obase + ds * 16) = u;
    }
  }
}

extern "C" void kernel_launch(void* const* d_in, const int* in_sizes, int n_in,
                              void* d_out, int out_size, void* d_ws, size_t ws_size,
                              hipStream_t stream) {
  const float* x  = (const float*)d_in[0];
  const float* Wq = (const float*)d_in[1];
  const float* Wk = (const float*)d_in[2];
  const float* Wv = (const float*)d_in[3];
  const float* Wo = (const float*)d_in[4];
  float* out = (float*)d_out;

  unsigned short* ws = (unsigned short*)d_ws;
  unsigned short* xb  = ws;                              // [4096][2048]
  unsigned short* Wqt = xb  + (size_t)MTOT * HIDDEN;     // [2048][2048] (Wqt/Wkt/Wvt contiguous = Wqkvt)
  unsigned short* Wkt = Wqt + (size_t)NQ * HIDDEN;       // [512][2048]
  unsigned short* Wvt = Wkt + (size_t)NKVD * HIDDEN;     // [512][2048]
  unsigned short* Wot = Wvt + (size_t)NKVD * HIDDEN;     // [2048][2048]
  unsigned short* Qb  = Wot + (size_t)NQ * HIDDEN;       // [4096][2048]
  unsigned short* Kb  = Qb  + (size_t)MTOT * NQ;         // [4096][512]
  unsigned short* Vtb = Kb  + (size_t)MTOT * NKVD;       // [512][4096]  (V^T)
  unsigned short* Ab  = Vtb + (size_t)MTOT * NKVD;       // [4096][2048]

  prep<<<8192 + 160 * 64, 256, 0, stream>>>(x, xb, Wq, Wk, Wv, Wo, Wqt, Wkt, Wvt, Wot);

  gemm_qkv<<<dim3(NQKV / 256, MTOT / 256), 1024, 0, stream>>>(xb, Wqt, Qb, Kb, Vtb);

  flash_attn<<<dim3(16, NHEADS, BATCH), 256, 0, stream>>>(Qb, Kb, Vtb, Ab);

  gemm_o<<<dim3(HIDDEN / 128, MTOT / 128), 512, 0, stream>>>(Ab, Wot, out, MTOT, HIDDEN, NQ);
}